// Round 8
// baseline (539.487 us; speedup 1.0000x reference)
//
#include <hip/hip_runtime.h>

// Problem constants (fixed by the reference)
#define S_LEN 2048
#define B_DIM 16
#define D_DIM 256
#define K_DIM 2048
#define E_NUM 1048576

typedef __attribute__((ext_vector_type(4))) float f32x4;
typedef __attribute__((ext_vector_type(8))) short s16x8;
typedef __attribute__((ext_vector_type(4))) unsigned short u16x4;
typedef __attribute__((ext_vector_type(8))) unsigned short u16x8;

__device__ __forceinline__ unsigned short f2bf(float f) {
    unsigned int u = __float_as_uint(f);
    u += 0x7fffu + ((u >> 16) & 1u);   // round-to-nearest-even
    return (unsigned short)(u >> 16);
}

// K0: fused prep.
// blocks [0,2048): zero mw (16 B/thread)
// blocks [2048,2560): W (K,D) fp32 -> bf16
// blocks [2560,10752): M (S,B,D) fp32 -> Mbf (B,S,D) bf16 (transposed for GEMM reads)
__global__ void prep_kernel(const float* __restrict__ W, const float* __restrict__ M,
                            unsigned short* __restrict__ Wbf, unsigned short* __restrict__ Mbf,
                            unsigned long long* __restrict__ mw) {
    int bid = blockIdx.x;
    if (bid < 2048) {
        int t = bid * 256 + threadIdx.x;           // 524288 threads x 16B = 8 MB
        ((f32x4*)mw)[t] = (f32x4){0.f, 0.f, 0.f, 0.f};
    } else if (bid < 2560) {
        int t = (bid - 2048) * 256 + threadIdx.x;  // 131072 threads, 1 float4 each
        f32x4 v = ((const f32x4*)W)[t];
        u16x4 u;
        u.x = f2bf(v.x); u.y = f2bf(v.y); u.z = f2bf(v.z); u.w = f2bf(v.w);
        ((u16x4*)Wbf)[t] = u;
    } else {
        int t = (bid - 2560) * 256 + threadIdx.x;  // 2,097,152 threads, 1 float4 each
        f32x4 v = ((const f32x4*)M)[t];
        int flat4 = t * 4;                         // (s*16 + b)*256 + d
        int d0 = flat4 & 255;
        int sb = flat4 >> 8;
        int b  = sb & 15;
        int s  = sb >> 4;
        u16x4 u;
        u.x = f2bf(v.x); u.y = f2bf(v.y); u.z = f2bf(v.z); u.w = f2bf(v.w);
        *(u16x4*)&Mbf[((size_t)(b * S_LEN + s)) * D_DIM + d0] = u;
    }
}

// K2: build dedup bitmask: one uint64 per (b,k,s-block-of-64)
__global__ void maskbuild_kernel(const int* __restrict__ eb, const int* __restrict__ ij,
                                 unsigned long long* __restrict__ mw) {
    int e = blockIdx.x * 256 + threadIdx.x;
    int b = eb[e];
    int2 p = *(const int2*)&ij[2 * e];
    size_t w = ((size_t)(b * K_DIM + p.x)) * 32 + (p.y >> 6);
    atomicOr(&mw[w], 1ull << (p.y & 63));
}

// K3: row-owning two-pass fused kernel, 2-D wave split for LDS-read reuse.
// Block = (b, 128-k tile), 512 threads = 8 waves = 2 (ws, s-split) x 4 (wk, k-split).
// Each lane holds TWO B-fragments (kset=2 -> 32 k/wave): every A-fragment LDS
// read feeds 2 MFMAs -> LDS read bytes per output halved vs round 7.
// s-tile = 64 rows -> LDS 2x32KB (+2KB reduce scratch) -> 2 blocks/CU, 4 waves/SIMD.
// No max-subtraction (x ~ N(0,1); exp safe in fp32). Per-lane Z/Ze partials,
// reduced once after pass 1 (shfl over g, LDS exchange over the ws pair).
__launch_bounds__(512, 4)
__global__ void gemm5_kernel(const unsigned short* __restrict__ Mbf,
                             const unsigned short* __restrict__ Wbf,
                             const unsigned long long* __restrict__ mw,
                             float* __restrict__ out) {
    __shared__ unsigned short Msh[2][64 * 256];   // 2 x 32KB, swizzled: slot = col16 ^ (row&7)
    __shared__ float smZ[8][2][16];               // per-wave partial Z  [w][ks][r]
    __shared__ float smE[8][2][16];               // per-wave partial Ze

    const int tid  = threadIdx.x;
    const int x    = blockIdx.x;
    // XCD-locality: the 16 blocks sharing batch b land on one XCD (2 b's/XCD)
    const int b    = ((x & 7) << 1) | ((x >> 3) & 1);
    const int k0   = (x >> 4) * 128;
    const int lane = tid & 63;
    const int w    = tid >> 6;        // wave 0..7
    const int wk   = w & 3;           // k-group 0..3
    const int ws   = w >> 2;          // s-group 0..1
    const int r    = lane & 15;
    const int g    = lane >> 4;       // 0..3

    const unsigned short* MB = Mbf + (size_t)b * S_LEN * D_DIM;
    const int kc0 = k0 + wk * 32 + r;            // lane's first k column
    const size_t orow0 = (size_t)(b * K_DIM + kc0) * S_LEN;
    const size_t mrow0 = (size_t)(b * K_DIM + kc0) * 32;

    // B-fragments in registers, loaded once: rows kc0, kc0+16
    s16x8 breg[2][8];
    #pragma unroll
    for (int ks = 0; ks < 2; ++ks)
        #pragma unroll
        for (int d = 0; d < 8; ++d)
            breg[ks][d] = *(const s16x8*)&Wbf[(size_t)(kc0 + ks * 16) * D_DIM + d * 32 + g * 8];

    const int lrh  = lane >> 5;   // 0/1: which of the 2 rows per 1KB chunk
    const int lc16 = lane & 31;   // physical 16B slot within row

    // Stage 64-row s-tile into Msh[bufi]: linear LDS dest (global_load_lds),
    // inverse-swizzled per-lane global source. Each wave stages 8 rows (4 gll).
    auto stage = [&](int bufi, int t) {
        const int s0 = t * 64;
        #pragma unroll
        for (int c = 0; c < 4; ++c) {
            const int row   = w * 8 + c * 2 + lrh;
            const int col16 = lc16 ^ (row & 7);
            const unsigned short* src = MB + (size_t)(s0 + row) * D_DIM + col16 * 8;
            char* dst = (char*)(&Msh[bufi][0]) + w * 4096 + c * 1024;  // wave-uniform base
            __builtin_amdgcn_global_load_lds(
                (__attribute__((address_space(1))) const void*)src,
                (__attribute__((address_space(3))) void*)dst, 16, 0, 0);
        }
    };

    float Zl[2]  = {0.f, 0.f};
    float Zel[2] = {0.f, 0.f};

    // ---------------- Pass 1: per-lane partial sums ----------------
    stage(0, 0);
    unsigned long long wn0 = mw[mrow0], wn1 = mw[mrow0 + 512];
    __syncthreads();

    for (int t = 0; t < 32; ++t) {
        if (t < 31) stage((t & 1) ^ 1, t + 1);           // prefetch next tile
        const unsigned long long wv0 = wn0, wv1 = wn1;
        if (t < 31) { wn0 = mw[mrow0 + t + 1]; wn1 = mw[mrow0 + 512 + t + 1]; }
        const unsigned short* cur = &Msh[t & 1][0];

        f32x4 acc[2][2];
        #pragma unroll
        for (int q = 0; q < 2; ++q)
            #pragma unroll
            for (int ks = 0; ks < 2; ++ks) acc[q][ks] = (f32x4){0.f, 0.f, 0.f, 0.f};

        #pragma unroll
        for (int d = 0; d < 8; ++d) {
            const int acol = ((d * 4 + g) ^ (r & 7)) * 8;
            #pragma unroll
            for (int q = 0; q < 2; ++q) {
                s16x8 a = *(const s16x8*)&cur[(ws * 32 + q * 16 + r) * 256 + acol];
                acc[q][0] = __builtin_amdgcn_mfma_f32_16x16x32_bf16(a, breg[0][d], acc[q][0], 0, 0, 0);
                acc[q][1] = __builtin_amdgcn_mfma_f32_16x16x32_bf16(a, breg[1][d], acc[q][1], 0, 0, 0);
            }
        }

        #pragma unroll
        for (int q = 0; q < 2; ++q) {
            const int sh = ws * 32 + q * 16 + g * 4;
            #pragma unroll
            for (int rr = 0; rr < 4; ++rr) {
                float e0 = __expf(acc[q][0][rr]);
                float e1 = __expf(acc[q][1][rr]);
                Zl[0] += e0; Zl[1] += e1;
                Zel[0] += ((wv0 >> (sh + rr)) & 1ull) ? e0 : 0.f;
                Zel[1] += ((wv1 >> (sh + rr)) & 1ull) ? e1 : 0.f;
            }
        }
        __syncthreads();   // stage(t+1) drained + all reads of cur done
    }

    // Reduce over g (shfl), then over the ws-pair (LDS), once for the kernel.
    #pragma unroll
    for (int ks = 0; ks < 2; ++ks) {
        Zl[ks]  += __shfl_xor(Zl[ks], 16);  Zl[ks]  += __shfl_xor(Zl[ks], 32);
        Zel[ks] += __shfl_xor(Zel[ks], 16); Zel[ks] += __shfl_xor(Zel[ks], 32);
    }
    if (g == 0) {
        smZ[w][0][r] = Zl[0]; smZ[w][1][r] = Zl[1];
        smE[w][0][r] = Zel[0]; smE[w][1][r] = Zel[1];
    }
    __syncthreads();
    float rdv[2];
    #pragma unroll
    for (int ks = 0; ks < 2; ++ks) {
        float Z  = Zl[ks]  + smZ[w ^ 4][ks][r];
        float Ze = Zel[ks] + smE[w ^ 4][ks][r];
        rdv[ks] = 1.0f / (1e-10f * (Z - Ze) + Ze);
    }

    // ---------------- Pass 2: recompute + final write ----------------
    stage(0, 0);
    wn0 = mw[mrow0]; wn1 = mw[mrow0 + 512];
    __syncthreads();

    for (int t = 0; t < 32; ++t) {
        if (t < 31) stage((t & 1) ^ 1, t + 1);
        const unsigned long long wv0 = wn0, wv1 = wn1;
        if (t < 31) { wn0 = mw[mrow0 + t + 1]; wn1 = mw[mrow0 + 512 + t + 1]; }
        const unsigned short* cur = &Msh[t & 1][0];

        f32x4 acc[2][2];
        #pragma unroll
        for (int q = 0; q < 2; ++q)
            #pragma unroll
            for (int ks = 0; ks < 2; ++ks) acc[q][ks] = (f32x4){0.f, 0.f, 0.f, 0.f};

        #pragma unroll
        for (int d = 0; d < 8; ++d) {
            const int acol = ((d * 4 + g) ^ (r & 7)) * 8;
            #pragma unroll
            for (int q = 0; q < 2; ++q) {
                s16x8 a = *(const s16x8*)&cur[(ws * 32 + q * 16 + r) * 256 + acol];
                acc[q][0] = __builtin_amdgcn_mfma_f32_16x16x32_bf16(a, breg[0][d], acc[q][0], 0, 0, 0);
                acc[q][1] = __builtin_amdgcn_mfma_f32_16x16x32_bf16(a, breg[1][d], acc[q][1], 0, 0, 0);
            }
        }

        #pragma unroll
        for (int q = 0; q < 2; ++q) {
            const int sh = ws * 32 + q * 16 + g * 4;
            const size_t so = (size_t)(t * 64 + ws * 32 + q * 16 + g * 4);
            #pragma unroll
            for (int ks = 0; ks < 2; ++ks) {
                const unsigned long long bits = ks ? wv1 : wv0;
                f32x4 ov;
                #pragma unroll
                for (int rr = 0; rr < 4; ++rr) {
                    bool edge = (bits >> (sh + rr)) & 1ull;
                    ov[rr] = edge ? __expf(acc[q][ks][rr]) * rdv[ks] : 0.f;
                }
                // Non-temporal: keep the 268MB output stream out of L2
                __builtin_nontemporal_store(ov,
                    (f32x4*)&out[orow0 + (size_t)ks * 16 * S_LEN + so]);
            }
        }
        __syncthreads();
    }
}

extern "C" void kernel_launch(void* const* d_in, const int* in_sizes, int n_in,
                              void* d_out, int out_size, void* d_ws, size_t ws_size,
                              hipStream_t stream) {
    (void)in_sizes; (void)n_in; (void)ws_size; (void)out_size;
    const float* M  = (const float*)d_in[0];
    const float* W  = (const float*)d_in[1];
    // d_in[2] = lengths: unused by the reference computation
    const int* eb   = (const int*)d_in[3];
    const int* ij   = (const int*)d_in[4];
    float* out      = (float*)d_out;
    char* ws        = (char*)d_ws;

    // Workspace layout (26.2 MB total)
    unsigned long long* mw = (unsigned long long*)ws;            //  8,388,608
    unsigned short* Wbf = (unsigned short*)(ws + 8388608);       //  1,048,576
    unsigned short* Mbf = (unsigned short*)(ws + 9437184);       // 16,777,216

    prep_kernel<<<10752, 256, 0, stream>>>(W, M, Wbf, Mbf, mw);
    maskbuild_kernel<<<E_NUM / 256, 256, 0, stream>>>(eb, ij, mw);
    gemm5_kernel<<<256, 512, 0, stream>>>(Mbf, Wbf, mw, out);
}

// Round 9
// 204.684 us; speedup vs baseline: 2.6357x; 2.6357x over previous
//
#include <hip/hip_runtime.h>

// Problem constants (fixed by the reference)
#define S_LEN 2048
#define B_DIM 16
#define D_DIM 256
#define K_DIM 2048
#define E_NUM 1048576

typedef __attribute__((ext_vector_type(4))) float f32x4;
typedef __attribute__((ext_vector_type(8))) short s16x8;
typedef __attribute__((ext_vector_type(4))) unsigned short u16x4;
typedef __attribute__((ext_vector_type(8))) unsigned short u16x8;

__device__ __forceinline__ unsigned short f2bf(float f) {
    unsigned int u = __float_as_uint(f);
    u += 0x7fffu + ((u >> 16) & 1u);   // round-to-nearest-even
    return (unsigned short)(u >> 16);
}

// K0: fused prep.
// blocks [0,2048): zero mw (16 B/thread)
// blocks [2048,2560): W (K,D) fp32 -> bf16
// blocks [2560,10752): M (S,B,D) fp32 -> Mbf (B,S,D) bf16 (transposed for GEMM reads)
__global__ void prep_kernel(const float* __restrict__ W, const float* __restrict__ M,
                            unsigned short* __restrict__ Wbf, unsigned short* __restrict__ Mbf,
                            unsigned long long* __restrict__ mw) {
    int bid = blockIdx.x;
    if (bid < 2048) {
        int t = bid * 256 + threadIdx.x;           // 524288 threads x 16B = 8 MB
        ((f32x4*)mw)[t] = (f32x4){0.f, 0.f, 0.f, 0.f};
    } else if (bid < 2560) {
        int t = (bid - 2048) * 256 + threadIdx.x;  // 131072 threads, 1 float4 each
        f32x4 v = ((const f32x4*)W)[t];
        u16x4 u;
        u.x = f2bf(v.x); u.y = f2bf(v.y); u.z = f2bf(v.z); u.w = f2bf(v.w);
        ((u16x4*)Wbf)[t] = u;
    } else {
        int t = (bid - 2560) * 256 + threadIdx.x;  // 2,097,152 threads, 1 float4 each
        f32x4 v = ((const f32x4*)M)[t];
        int flat4 = t * 4;                         // (s*16 + b)*256 + d
        int d0 = flat4 & 255;
        int sb = flat4 >> 8;
        int b  = sb & 15;
        int s  = sb >> 4;
        u16x4 u;
        u.x = f2bf(v.x); u.y = f2bf(v.y); u.z = f2bf(v.z); u.w = f2bf(v.w);
        *(u16x4*)&Mbf[((size_t)(b * S_LEN + s)) * D_DIM + d0] = u;
    }
}

// K2: build dedup bitmask: one uint64 per (b,k,s-block-of-64)
__global__ void maskbuild_kernel(const int* __restrict__ eb, const int* __restrict__ ij,
                                 unsigned long long* __restrict__ mw) {
    int e = blockIdx.x * 256 + threadIdx.x;
    int b = eb[e];
    int2 p = *(const int2*)&ij[2 * e];
    size_t w = ((size_t)(b * K_DIM + p.x)) * 32 + (p.y >> 6);
    atomicOr(&mw[w], 1ull << (p.y & 63));
}

// K3: row-owning two-pass fused kernel, 2-D wave split for LDS-read reuse.
// Block = (b, 128-k tile), 512 threads = 8 waves = 2 (ws, s-split) x 4 (wk, k-split).
// Each lane holds TWO B-fragments (kset=2 -> 32 k/wave): every A-fragment LDS
// read feeds 2 MFMAs -> LDS read bytes per output halved.
// s-tile = 64 rows -> LDS 2x32KB (+2KB reduce scratch) -> 2 blocks/CU (LDS-limited).
// __launch_bounds__(512,2): round 8's (512,4) capped VGPR at 64 -> breg alone
// is 64 -> catastrophic spills (FETCH 1.16GB of scratch traffic). (512,2) -> ~128 cap.
// No max-subtraction (x ~ N(0,1); exp safe in fp32). Per-lane Z/Ze partials,
// reduced once after pass 1 (shfl over g, LDS exchange over the ws pair).
__launch_bounds__(512, 2)
__global__ void gemm5_kernel(const unsigned short* __restrict__ Mbf,
                             const unsigned short* __restrict__ Wbf,
                             const unsigned long long* __restrict__ mw,
                             float* __restrict__ out) {
    __shared__ unsigned short Msh[2][64 * 256];   // 2 x 32KB, swizzled: slot = col16 ^ (row&7)
    __shared__ float smZ[8][2][16];               // per-wave partial Z  [w][ks][r]
    __shared__ float smE[8][2][16];               // per-wave partial Ze

    const int tid  = threadIdx.x;
    const int x    = blockIdx.x;
    // XCD-locality: the 16 blocks sharing batch b land on one XCD (2 b's/XCD)
    const int b    = ((x & 7) << 1) | ((x >> 3) & 1);
    const int k0   = (x >> 4) * 128;
    const int lane = tid & 63;
    const int w    = tid >> 6;        // wave 0..7
    const int wk   = w & 3;           // k-group 0..3
    const int ws   = w >> 2;          // s-group 0..1
    const int r    = lane & 15;
    const int g    = lane >> 4;       // 0..3

    const unsigned short* MB = Mbf + (size_t)b * S_LEN * D_DIM;
    const int kc0 = k0 + wk * 32 + r;            // lane's first k column
    const size_t orow0 = (size_t)(b * K_DIM + kc0) * S_LEN;
    const size_t mrow0 = (size_t)(b * K_DIM + kc0) * 32;

    // B-fragments in registers, loaded once: rows kc0, kc0+16
    s16x8 breg[2][8];
    #pragma unroll
    for (int ks = 0; ks < 2; ++ks)
        #pragma unroll
        for (int d = 0; d < 8; ++d)
            breg[ks][d] = *(const s16x8*)&Wbf[(size_t)(kc0 + ks * 16) * D_DIM + d * 32 + g * 8];

    const int lrh  = lane >> 5;   // 0/1: which of the 2 rows per 1KB chunk
    const int lc16 = lane & 31;   // physical 16B slot within row

    // Stage 64-row s-tile into Msh[bufi]: linear LDS dest (global_load_lds),
    // inverse-swizzled per-lane global source. Each wave stages 8 rows (4 gll).
    auto stage = [&](int bufi, int t) {
        const int s0 = t * 64;
        #pragma unroll
        for (int c = 0; c < 4; ++c) {
            const int row   = w * 8 + c * 2 + lrh;
            const int col16 = lc16 ^ (row & 7);
            const unsigned short* src = MB + (size_t)(s0 + row) * D_DIM + col16 * 8;
            char* dst = (char*)(&Msh[bufi][0]) + w * 4096 + c * 1024;  // wave-uniform base
            __builtin_amdgcn_global_load_lds(
                (__attribute__((address_space(1))) const void*)src,
                (__attribute__((address_space(3))) void*)dst, 16, 0, 0);
        }
    };

    float Zl[2]  = {0.f, 0.f};
    float Zel[2] = {0.f, 0.f};

    // ---------------- Pass 1: per-lane partial sums ----------------
    stage(0, 0);
    unsigned long long wn0 = mw[mrow0], wn1 = mw[mrow0 + 512];
    __syncthreads();

    for (int t = 0; t < 32; ++t) {
        if (t < 31) stage((t & 1) ^ 1, t + 1);           // prefetch next tile
        const unsigned long long wv0 = wn0, wv1 = wn1;
        if (t < 31) { wn0 = mw[mrow0 + t + 1]; wn1 = mw[mrow0 + 512 + t + 1]; }
        const unsigned short* cur = &Msh[t & 1][0];

        f32x4 acc[2][2];
        #pragma unroll
        for (int q = 0; q < 2; ++q)
            #pragma unroll
            for (int ks = 0; ks < 2; ++ks) acc[q][ks] = (f32x4){0.f, 0.f, 0.f, 0.f};

        #pragma unroll
        for (int d = 0; d < 8; ++d) {
            const int acol = ((d * 4 + g) ^ (r & 7)) * 8;
            #pragma unroll
            for (int q = 0; q < 2; ++q) {
                s16x8 a = *(const s16x8*)&cur[(ws * 32 + q * 16 + r) * 256 + acol];
                acc[q][0] = __builtin_amdgcn_mfma_f32_16x16x32_bf16(a, breg[0][d], acc[q][0], 0, 0, 0);
                acc[q][1] = __builtin_amdgcn_mfma_f32_16x16x32_bf16(a, breg[1][d], acc[q][1], 0, 0, 0);
            }
        }

        #pragma unroll
        for (int q = 0; q < 2; ++q) {
            const int sh = ws * 32 + q * 16 + g * 4;
            #pragma unroll
            for (int rr = 0; rr < 4; ++rr) {
                float e0 = __expf(acc[q][0][rr]);
                float e1 = __expf(acc[q][1][rr]);
                Zl[0] += e0; Zl[1] += e1;
                Zel[0] += ((wv0 >> (sh + rr)) & 1ull) ? e0 : 0.f;
                Zel[1] += ((wv1 >> (sh + rr)) & 1ull) ? e1 : 0.f;
            }
        }
        __syncthreads();   // stage(t+1) drained + all reads of cur done
    }

    // Reduce over g (shfl), then over the ws-pair (LDS), once for the kernel.
    #pragma unroll
    for (int ks = 0; ks < 2; ++ks) {
        Zl[ks]  += __shfl_xor(Zl[ks], 16);  Zl[ks]  += __shfl_xor(Zl[ks], 32);
        Zel[ks] += __shfl_xor(Zel[ks], 16); Zel[ks] += __shfl_xor(Zel[ks], 32);
    }
    if (g == 0) {
        smZ[w][0][r] = Zl[0]; smZ[w][1][r] = Zl[1];
        smE[w][0][r] = Zel[0]; smE[w][1][r] = Zel[1];
    }
    __syncthreads();
    float rdv[2];
    #pragma unroll
    for (int ks = 0; ks < 2; ++ks) {
        float Z  = Zl[ks]  + smZ[w ^ 4][ks][r];
        float Ze = Zel[ks] + smE[w ^ 4][ks][r];
        rdv[ks] = 1.0f / (1e-10f * (Z - Ze) + Ze);
    }

    // ---------------- Pass 2: recompute + final write ----------------
    stage(0, 0);
    wn0 = mw[mrow0]; wn1 = mw[mrow0 + 512];
    __syncthreads();

    for (int t = 0; t < 32; ++t) {
        if (t < 31) stage((t & 1) ^ 1, t + 1);
        const unsigned long long wv0 = wn0, wv1 = wn1;
        if (t < 31) { wn0 = mw[mrow0 + t + 1]; wn1 = mw[mrow0 + 512 + t + 1]; }
        const unsigned short* cur = &Msh[t & 1][0];

        f32x4 acc[2][2];
        #pragma unroll
        for (int q = 0; q < 2; ++q)
            #pragma unroll
            for (int ks = 0; ks < 2; ++ks) acc[q][ks] = (f32x4){0.f, 0.f, 0.f, 0.f};

        #pragma unroll
        for (int d = 0; d < 8; ++d) {
            const int acol = ((d * 4 + g) ^ (r & 7)) * 8;
            #pragma unroll
            for (int q = 0; q < 2; ++q) {
                s16x8 a = *(const s16x8*)&cur[(ws * 32 + q * 16 + r) * 256 + acol];
                acc[q][0] = __builtin_amdgcn_mfma_f32_16x16x32_bf16(a, breg[0][d], acc[q][0], 0, 0, 0);
                acc[q][1] = __builtin_amdgcn_mfma_f32_16x16x32_bf16(a, breg[1][d], acc[q][1], 0, 0, 0);
            }
        }

        #pragma unroll
        for (int q = 0; q < 2; ++q) {
            const int sh = ws * 32 + q * 16 + g * 4;
            const size_t so = (size_t)(t * 64 + ws * 32 + q * 16 + g * 4);
            #pragma unroll
            for (int ks = 0; ks < 2; ++ks) {
                const unsigned long long bits = ks ? wv1 : wv0;
                f32x4 ov;
                #pragma unroll
                for (int rr = 0; rr < 4; ++rr) {
                    bool edge = (bits >> (sh + rr)) & 1ull;
                    ov[rr] = edge ? __expf(acc[q][ks][rr]) * rdv[ks] : 0.f;
                }
                // Non-temporal: keep the 268MB output stream out of L2
                __builtin_nontemporal_store(ov,
                    (f32x4*)&out[orow0 + (size_t)ks * 16 * S_LEN + so]);
            }
        }
        __syncthreads();
    }
}

extern "C" void kernel_launch(void* const* d_in, const int* in_sizes, int n_in,
                              void* d_out, int out_size, void* d_ws, size_t ws_size,
                              hipStream_t stream) {
    (void)in_sizes; (void)n_in; (void)ws_size; (void)out_size;
    const float* M  = (const float*)d_in[0];
    const float* W  = (const float*)d_in[1];
    // d_in[2] = lengths: unused by the reference computation
    const int* eb   = (const int*)d_in[3];
    const int* ij   = (const int*)d_in[4];
    float* out      = (float*)d_out;
    char* ws        = (char*)d_ws;

    // Workspace layout (26.2 MB total)
    unsigned long long* mw = (unsigned long long*)ws;            //  8,388,608
    unsigned short* Wbf = (unsigned short*)(ws + 8388608);       //  1,048,576
    unsigned short* Mbf = (unsigned short*)(ws + 9437184);       // 16,777,216

    prep_kernel<<<10752, 256, 0, stream>>>(W, M, Wbf, Mbf, mw);
    maskbuild_kernel<<<E_NUM / 256, 256, 0, stream>>>(eb, ij, mw);
    gemm5_kernel<<<256, 512, 0, stream>>>(Mbf, Wbf, mw, out);
}